// Round 9
// baseline (60.112 us; speedup 1.0000x reference)
//
#include <hip/hip_runtime.h>
#include <hip/hip_bf16.h>
#include <cmath>

#define CT    1024   // C*T channels
#define PIX   1296   // 36*36 pixels
#define BATCH 16
#define NNEUR 4096
#define HW    36
#define NBINS (HW * HW)
#define NPAIR (NNEUR * 4)        // 16384 (neuron, corner) pairs
#define BCT   (BATCH * CT)       // stride of one pixel in feat

typedef short short8 __attribute__((ext_vector_type(8)));
typedef float f32x4  __attribute__((ext_vector_type(4)));

__device__ __forceinline__ unsigned short bfu(float f) {
    __hip_bfloat16 h = __float2bfloat16(f);
    return *reinterpret_cast<unsigned short*>(&h);
}

// ---------- Kernel 1: transpose + pack x [B,CT,36,36] f32 -> feat [pix][B][CT] bf16
__global__ __launch_bounds__(256) void transpose_bf16_kernel(
    const float* __restrict__ x, __hip_bfloat16* __restrict__ feat)
{
    __shared__ unsigned short lds[64][34];
    const int b      = blockIdx.z;
    const int ctBase = blockIdx.y * 64;
    const int pBase  = blockIdx.x * 32;
    const int t      = threadIdx.x;
    const size_t xb  = (size_t)b * CT * PIX;
    {
        const int r  = t >> 2;
        const int pc = (t & 3) * 8;
        const float* src = x + xb + (size_t)(ctBase + r) * PIX + pBase + pc;
        if (pBase + 32 <= PIX) {
            float4 a = reinterpret_cast<const float4*>(src)[0];
            float4 c = reinterpret_cast<const float4*>(src)[1];
            lds[r][pc + 0] = bfu(a.x); lds[r][pc + 1] = bfu(a.y);
            lds[r][pc + 2] = bfu(a.z); lds[r][pc + 3] = bfu(a.w);
            lds[r][pc + 4] = bfu(c.x); lds[r][pc + 5] = bfu(c.y);
            lds[r][pc + 6] = bfu(c.z); lds[r][pc + 7] = bfu(c.w);
        } else {
#pragma unroll
            for (int i = 0; i < 8; ++i) {
                int p = pBase + pc + i;
                lds[r][pc + i] = (p < PIX) ? bfu(src[i]) : (unsigned short)0;
            }
        }
    }
    __syncthreads();
    const int pr = t >> 3;
    const int cc = (t & 7) * 8;
    if (pBase + pr < PIX) {
        unsigned short o[8];
#pragma unroll
        for (int i = 0; i < 8; ++i) o[i] = lds[cc + i][pr];
        const size_t off = ((size_t)(pBase + pr) * BATCH + b) * CT + ctBase + cc;
        *reinterpret_cast<uint4*>((unsigned short*)feat + off) = *reinterpret_cast<uint4*>(o);
    }
}

// ---------- Kernel 2: block 0 = counting sort of (neuron,corner) PAIRS by
// corner pixel (clamped); blocks 1..1024 = pack W f32 -> bf16.
__global__ __launch_bounds__(1024) void sortpack_kernel(
    const float* __restrict__ mu,
    int* __restrict__ plist,      // [NPAIR] sorted pair ids (n*4+k)
    int* __restrict__ pstart,     // [PIX+1] bin starts
    const float* __restrict__ W, __hip_bfloat16* __restrict__ Wb)
{
    const int t = threadIdx.x;
    if (blockIdx.x != 0) {
        const int i = (blockIdx.x - 1) * 1024 + t;   // one float4 per thread
        const float4 v = reinterpret_cast<const float4*>(W)[i];
        unsigned short o[4] = { bfu(v.x), bfu(v.y), bfu(v.z), bfu(v.w) };
        reinterpret_cast<ushort4*>(Wb)[i] = *reinterpret_cast<ushort4*>(o);
        return;
    }

    __shared__ int hist[NBINS];
    __shared__ int chunkSum[48];
    for (int i = t; i < NBINS; i += 1024) hist[i] = 0;
    __syncthreads();

    int key[16];                   // 4 neurons x 4 corners per thread
#pragma unroll
    for (int nn = 0; nn < 4; ++nn) {
        const int n = t * 4 + nn;
        float gx = fminf(fmaxf(mu[2 * n],     -1.f), 1.f);
        float gy = fminf(fmaxf(mu[2 * n + 1], -1.f), 1.f);
        float ix = (gx + 1.f) * (HW * 0.5f) - 0.5f;
        float iy = (gy + 1.f) * (HW * 0.5f) - 0.5f;
        int x0 = (int)floorf(ix), y0 = (int)floorf(iy);
#pragma unroll
        for (int k = 0; k < 4; ++k) {
            int xi = min(max(x0 + (k & 1), 0), HW - 1);
            int yi = min(max(y0 + (k >> 1), 0), HW - 1);
            key[nn * 4 + k] = yi * HW + xi;
            atomicAdd(&hist[key[nn * 4 + k]], 1);
        }
    }
    __syncthreads();
    if (t < 41) {
        int s = 0;
        for (int i = 0; i < 32; ++i) {
            int idx = t * 32 + i;
            if (idx < NBINS) s += hist[idx];
        }
        chunkSum[t] = s;
    }
    __syncthreads();
    if (t == 0) {
        int run = 0;
        for (int i = 0; i < 41; ++i) { int v = chunkSum[i]; chunkSum[i] = run; run += v; }
    }
    __syncthreads();
    if (t < 41) {
        int run = chunkSum[t];
        for (int i = 0; i < 32; ++i) {
            int idx = t * 32 + i;
            if (idx < NBINS) { int v = hist[idx]; hist[idx] = run; run += v; }
        }
    }
    __syncthreads();
    // publish bin starts BEFORE scatter mutates hist
    for (int i = t; i < NBINS; i += 1024) pstart[i] = hist[i];
    if (t == 0) pstart[NBINS] = NPAIR;
    __syncthreads();
#pragma unroll
    for (int nn = 0; nn < 4; ++nn) {
#pragma unroll
        for (int k = 0; k < 4; ++k) {
            const int pairid = (t * 4 + nn) * 4 + k;
            const int pos = atomicAdd(&hist[key[nn * 4 + k]], 1);
            plist[pos] = pairid;
        }
    }
}

// ---------- Kernel 3: pixel-centric MFMA GEMM.
// Block = pixel p, 4 waves. D[16 batch][16 pairs] = feat[p] (16x1024) x W^T.
// Wave w covers channels [256w, 256w+256) via 8 x mfma_16x16x32; LDS reduce.
// Raw dots scattered to pd[pairid][16 batches] (order-independent => deterministic).
__global__ __launch_bounds__(256) void pixgemm_kernel(
    const __hip_bfloat16* __restrict__ feat,  // [pix][B][CT]
    const __hip_bfloat16* __restrict__ Wb,    // [N][CT]
    const int* __restrict__ plist,
    const int* __restrict__ pstart,
    float* __restrict__ pd)                   // [NPAIR][16]
{
    const int p  = blockIdx.x;
    const int t  = threadIdx.x;
    const int wv = t >> 6;          // wave 0..3
    const int l  = t & 63;          // lane
    const int start = pstart[p];
    const int cnt   = pstart[p + 1] - start;
    const int ntile = (cnt + 15) >> 4;

    __shared__ f32x4 red[4][64];    // per-wave partial C fragments (4 KB)

    // A fragment base: lane l reads feat[p][b = l&15][k = 8*(l>>4) + j]
    const unsigned short* fbase = (const unsigned short*)feat
        + (size_t)p * BCT + (size_t)(l & 15) * CT + ((l >> 4) * 8) + wv * 256;

    for (int tile = 0; tile < ntile; ++tile) {
        const int slot = tile * 16 + (l & 15);
        const int v    = (slot < cnt) ? plist[start + slot] : 0;
        const unsigned short* wrow = (const unsigned short*)Wb
            + (size_t)(v >> 2) * CT + ((l >> 4) * 8) + wv * 256;

        f32x4 acc = {0.f, 0.f, 0.f, 0.f};
#pragma unroll
        for (int s = 0; s < 8; ++s) {
            const short8 av = *reinterpret_cast<const short8*>(fbase + s * 32);
            const short8 bv = *reinterpret_cast<const short8*>(wrow  + s * 32);
            acc = __builtin_amdgcn_mfma_f32_16x16x32_bf16(av, bv, acc, 0, 0, 0);
        }
        red[wv][l] = acc;
        __syncthreads();
        if (wv == 0 && slot < cnt) {
            const f32x4 a0 = red[0][l], a1 = red[1][l], a2 = red[2][l], a3 = red[3][l];
            float4 o;
            o.x = a0[0] + a1[0] + a2[0] + a3[0];
            o.y = a0[1] + a1[1] + a2[1] + a3[1];
            o.z = a0[2] + a1[2] + a2[2] + a3[2];
            o.w = a0[3] + a1[3] + a2[3] + a3[3];
            // lane l: col = l&15 (pair slot), rows = (l>>4)*4 + 0..3 (batch)
            *reinterpret_cast<float4*>(pd + (size_t)v * 16 + (l >> 4) * 4) = o;
        }
        __syncthreads();
    }
}

// ---------- Kernel 4: combine. out[b,n] = elu(bias + sum_k cw_k * pd[n*4+k][b]) + 1
__global__ __launch_bounds__(256) void finish_kernel(
    const float* __restrict__ pd, const float* __restrict__ mu,
    const float* __restrict__ bias, float* __restrict__ out)
{
    const int i = blockIdx.x * 256 + threadIdx.x;   // over NNEUR*BATCH
    const int n = i >> 4, b = i & 15;

    float gx = fminf(fmaxf(mu[2 * n],     -1.f), 1.f);
    float gy = fminf(fmaxf(mu[2 * n + 1], -1.f), 1.f);
    float ix = (gx + 1.f) * (HW * 0.5f) - 0.5f;
    float iy = (gy + 1.f) * (HW * 0.5f) - 0.5f;
    float x0f = floorf(ix), y0f = floorf(iy);
    float wx1 = ix - x0f, wx0 = 1.f - wx1;
    float wy1 = iy - y0f, wy0 = 1.f - wy1;
    int x0 = (int)x0f, y0 = (int)y0f;

    float y = bias[n];
#pragma unroll
    for (int k = 0; k < 4; ++k) {
        int xx = x0 + (k & 1), yy = y0 + (k >> 1);
        bool valid = (xx >= 0) && (xx < HW) && (yy >= 0) && (yy < HW);
        float cw = ((k & 1) ? wx1 : wx0) * ((k >> 1) ? wy1 : wy0) * (valid ? 1.f : 0.f);
        y = fmaf(cw, pd[(size_t)(n * 4 + k) * 16 + b], y);
    }
    out[(size_t)b * NNEUR + n] = (y > 0.f) ? (y + 1.f) : expf(y);  // elu(y)+1
}

// ---------- fallback: fp32 strided path straight from x (ws too small)
__global__ __launch_bounds__(256) void readout_f32_strided_kernel(
    const float* __restrict__ x,
    const float* __restrict__ mu,
    const float* __restrict__ Wm,
    const float* __restrict__ bias,
    float* __restrict__ out)
{
    const int n = blockIdx.x;
    const int t = threadIdx.x;
    const float4 w4 = reinterpret_cast<const float4*>(Wm + (size_t)n * CT)[t];
    float gx = fminf(fmaxf(mu[2 * n],     -1.f), 1.f);
    float gy = fminf(fmaxf(mu[2 * n + 1], -1.f), 1.f);
    float ix = (gx + 1.f) * (HW * 0.5f) - 0.5f;
    float iy = (gy + 1.f) * (HW * 0.5f) - 0.5f;
    float x0f = floorf(ix), y0f = floorf(iy);
    float wx1 = ix - x0f, wx0 = 1.f - wx1;
    float wy1 = iy - y0f, wy0 = 1.f - wy1;
    int x0 = (int)x0f, y0 = (int)y0f;
    float cw[4]; int cp[4];
#pragma unroll
    for (int k = 0; k < 4; ++k) {
        int xx = x0 + (k & 1), yy = y0 + (k >> 1);
        bool valid = (xx >= 0) && (xx < HW) && (yy >= 0) && (yy < HW);
        int xi = min(max(xx, 0), HW - 1), yi = min(max(yy, 0), HW - 1);
        cp[k] = yi * HW + xi;
        cw[k] = ((k & 1) ? wx1 : wx0) * ((k >> 1) ? wy1 : wy0) * (valid ? 1.f : 0.f);
    }
    float acc[BATCH];
#pragma unroll
    for (int b = 0; b < BATCH; ++b) {
        float s = 0.f;
#pragma unroll
        for (int k = 0; k < 4; ++k) {
            if (cw[k] != 0.f) {
                const float* fp = x + (size_t)b * CT * PIX + cp[k];
                const int c0 = 4 * t;
                s += cw[k] * (fp[(size_t)(c0 + 0) * PIX] * w4.x
                            + fp[(size_t)(c0 + 1) * PIX] * w4.y
                            + fp[(size_t)(c0 + 2) * PIX] * w4.z
                            + fp[(size_t)(c0 + 3) * PIX] * w4.w);
            }
        }
        acc[b] = s;
    }
#pragma unroll
    for (int b = 0; b < BATCH; ++b) {
        float v = acc[b];
#pragma unroll
        for (int off = 32; off > 0; off >>= 1)
            v += __shfl_down(v, off, 64);
        acc[b] = v;
    }
    __shared__ float red[4][BATCH];
    const int wave = t >> 6, lane = t & 63;
    if (lane == 0) {
#pragma unroll
        for (int b = 0; b < BATCH; ++b) red[wave][b] = acc[b];
    }
    __syncthreads();
    if (t < BATCH) {
        float y = red[0][t] + red[1][t] + red[2][t] + red[3][t] + bias[n];
        out[(size_t)t * NNEUR + n] = (y > 0.f) ? (y + 1.f) : expf(y);
    }
}

extern "C" void kernel_launch(void* const* d_in, const int* in_sizes, int n_in,
                              void* d_out, int out_size, void* d_ws, size_t ws_size,
                              hipStream_t stream)
{
    const float* x    = (const float*)d_in[0];
    const float* mu   = (const float*)d_in[1];
    const float* Wm   = (const float*)d_in[3];
    const float* bias = (const float*)d_in[4];
    float* out = (float*)d_out;

    const size_t featBytes  = (size_t)BATCH * PIX * CT * sizeof(__hip_bfloat16); // 42.5 MB
    const size_t wBytes     = (size_t)NNEUR * CT * sizeof(__hip_bfloat16);       // 8.4 MB
    const size_t plistBytes = (size_t)NPAIR * sizeof(int);                       // 64 KB
    const size_t pstartBytes= 8192;                                              // padded
    const size_t pdBytes    = (size_t)NPAIR * 16 * sizeof(float);                // 1 MB

    if (ws_size >= featBytes + wBytes + plistBytes + pstartBytes + pdBytes) {
        char* wp = (char*)d_ws;
        __hip_bfloat16* feat = (__hip_bfloat16*)wp;                 wp += featBytes;
        __hip_bfloat16* Wb   = (__hip_bfloat16*)wp;                 wp += wBytes;
        int*   plist  = (int*)wp;                                   wp += plistBytes;
        int*   pstart = (int*)wp;                                   wp += pstartBytes;
        float* pd     = (float*)wp;

        dim3 tg((PIX + 31) / 32, CT / 64, BATCH);
        transpose_bf16_kernel<<<tg, 256, 0, stream>>>(x, feat);
        sortpack_kernel<<<1 + (NNEUR * CT / 4) / 1024, 1024, 0, stream>>>(
            mu, plist, pstart, Wm, Wb);
        pixgemm_kernel<<<PIX, 256, 0, stream>>>(feat, Wb, plist, pstart, pd);
        finish_kernel<<<(NNEUR * BATCH) / 256, 256, 0, stream>>>(pd, mu, bias, out);
    } else {
        readout_f32_strided_kernel<<<NNEUR, 256, 0, stream>>>(x, mu, Wm, bias, out);
    }
}